// Round 10
// baseline (466.999 us; speedup 1.0000x reference)
//
#include <hip/hip_runtime.h>
#include <hip/hip_bf16.h>
#include <cstdint>
#include <cstddef>

// Transformer block: B=2, T=2048, C=1024, H=16, HD=64.
// bf16 MFMA for all GEMM-shaped compute; fp32 for LN stats / softmax sums / residuals.
// R10: attn reverted to the R6 structure (single-buffer K/V, 2 barriers/chunk,
// reg-prefetch) but with 2-WAVE blocks (128 thr, 32 q-rows): 7 independent
// barrier domains/CU instead of 4, smaller sync groups, real scheduling slack
// for the causal tail. GEMMs unchanged from R6 (BK=64, XOR swizzle, XCD swizzle).
#define B_  2
#define T_  2048
#define C_  1024
#define H_  16
#define HD_ 64
#define M_TOT 4096   // B*T

typedef __bf16 bf16x8 __attribute__((ext_vector_type(8)));
typedef float  f32x4  __attribute__((ext_vector_type(4)));
typedef unsigned short u16;

__device__ __forceinline__ u16 f2bf(float f) {
  __hip_bfloat16 h = __float2bfloat16(f);
  return __builtin_bit_cast(u16, h);
}

// async global->LDS, 16B per lane; LDS dest is wave-uniform base + lane*16.
__device__ __forceinline__ void async_cp16(const u16* g, u16* l) {
  __builtin_amdgcn_global_load_lds(
      (const __attribute__((address_space(1))) void*)g,
      (__attribute__((address_space(3))) void*)l, 16, 0, 0);
}

// gelu_tanh: 0.5*x*(1+tanh z) == x * sigmoid(2z); overflow-safe via negative exp.
__device__ __forceinline__ float gelu_f(float x) {
  const float z = 0.7978845608028654f * (x + 0.044715f * x * x * x);
  return x / (1.0f + __expf(-2.0f * z));
}

// ---------------- LayerNorm (fp32 in -> bf16 out), one block per row ----------------
__global__ __launch_bounds__(256) void ln_bf16_kernel(
    const float* __restrict__ x, const float* __restrict__ g,
    const float* __restrict__ b, u16* __restrict__ out) {
  const int row = blockIdx.x;
  const int tid = threadIdx.x;
  const float4 v = reinterpret_cast<const float4*>(x)[row * 256 + tid];
  float s  = v.x + v.y + v.z + v.w;
  float sq = v.x * v.x + v.y * v.y + v.z * v.z + v.w * v.w;
#pragma unroll
  for (int off = 32; off > 0; off >>= 1) {
    s  += __shfl_xor(s, off);
    sq += __shfl_xor(sq, off);
  }
  __shared__ float red[8];
  const int wave = tid >> 6;
  if ((tid & 63) == 0) { red[wave] = s; red[4 + wave] = sq; }
  __syncthreads();
  s  = red[0] + red[1] + red[2] + red[3];
  sq = red[4] + red[5] + red[6] + red[7];
  const float mu   = s * (1.0f / 1024.0f);
  const float rstd = rsqrtf(sq * (1.0f / 1024.0f) - mu * mu + 1e-5f);
  const float4 gv = reinterpret_cast<const float4*>(g)[tid];
  const float4 bv = reinterpret_cast<const float4*>(b)[tid];
  ushort4 o;
  o.x = f2bf((v.x - mu) * rstd * gv.x + bv.x);
  o.y = f2bf((v.y - mu) * rstd * gv.y + bv.y);
  o.z = f2bf((v.z - mu) * rstd * gv.z + bv.z);
  o.w = f2bf((v.w - mu) * rstd * gv.w + bv.w);
  reinterpret_cast<ushort4*>(out)[row * 256 + tid] = o;
}

// ---------------- W[K][N] fp32 -> Wt[N][K] bf16 (tiled transpose+convert) ----------------
__global__ __launch_bounds__(256) void transpose_bf16_kernel(
    const float* __restrict__ W, u16* __restrict__ Wt, int K, int N) {
  __shared__ float tile[32][33];
  const int n0 = blockIdx.x * 32, k0 = blockIdx.y * 32;
  const int tx = threadIdx.x & 31;
  const int ty = threadIdx.x >> 5;  // 0..7
#pragma unroll
  for (int i = 0; i < 4; ++i)
    tile[ty + 8 * i][tx] = W[(k0 + ty + 8 * i) * (size_t)N + n0 + tx];
  __syncthreads();
#pragma unroll
  for (int i = 0; i < 4; ++i)
    Wt[(n0 + ty + 8 * i) * (size_t)K + k0 + tx] = f2bf(tile[tx][ty + 8 * i]);
}

// ---------------- bf16 MFMA GEMM: C[M,N] = A[M,K] @ Bt[N,K]^T, fused epilogues -------------
// Tile: BM x 128, BK=64. XOR-swizzled LDS (conflict-free), XCD-aware block swizzle.
// MODE 0: +bias, gelu -> bf16 out                      (fc)
// MODE 1: +bias, +resid(fp32) -> fp32                  (proj, fc2)
// MODE 3: +bias, scatter q(scaled)/k [B,H,T,HD], v transposed [B,H,HD,T]  (qkv)
template <int MODE, int BM>
__global__ __launch_bounds__(256, 2) void gemm_kernel(
    const u16* __restrict__ A, const u16* __restrict__ Bt,
    const float* __restrict__ bias, const float* __restrict__ resid,
    float* __restrict__ outf, u16* __restrict__ outb,
    u16* __restrict__ qo, u16* __restrict__ ko, u16* __restrict__ vto,
    int M, int N, int K, int logPer) {
  constexpr int MT = BM / 32;            // m-tiles of 16 per wave
  constexpr int AI = BM / 32;            // A staging instrs per wave (8 rows each)
  __shared__ __align__(16) u16 As[BM * 64];
  __shared__ __align__(16) u16 Bs[128 * 64];
  const int tid  = threadIdx.x;
  const int wave = tid >> 6, lane = tid & 63;
  const int col  = lane & 15, quad = lane >> 4;
  const int wm   = wave >> 1, wn = wave & 1;

  const int flat = blockIdx.y * gridDim.x + blockIdx.x;
  const int xcd = flat & 7, sl = flat >> 3;
  const int per = 1 << logPer;
  const int bm = (xcd << logPer) + (sl & (per - 1));
  const int bn = sl >> logPer;

  const int srow = lane >> 3, sc8 = lane & 7;
  const int kcs = (sc8 ^ srow) * 8;                  // XOR-swizzled global k offset
  const u16* ap = A  + (size_t)(bm * BM + wave * (BM / 4) + srow) * K + kcs;
  const u16* bp = Bt + (size_t)(bn * 128 + wave * 32 + srow) * K + kcs;
  u16* as_dst = As + wave * (BM / 4) * 64;
  u16* bs_dst = Bs + wave * 2048;

  f32x4 acc[MT][4] = {};

  for (int k0 = 0; k0 < K; k0 += 64) {
    __syncthreads();
#pragma unroll
    for (int i = 0; i < AI; ++i)
      async_cp16(ap + k0 + i * 8 * (size_t)K, as_dst + i * 512);
#pragma unroll
    for (int i = 0; i < 4; ++i)
      async_cp16(bp + k0 + i * 8 * (size_t)K, bs_dst + i * 512);
    __syncthreads();
#pragma unroll
    for (int kh = 0; kh < 2; ++kh) {
      const int ks = kh * 4;
      bf16x8 af[MT], bf[4];
#pragma unroll
      for (int mt = 0; mt < MT; ++mt) {
        const int row = wm * (BM / 2) + mt * 16 + col;
        af[mt] = *reinterpret_cast<const bf16x8*>(&As[row * 64 + ((ks + quad) ^ (col & 7)) * 8]);
      }
#pragma unroll
      for (int nt = 0; nt < 4; ++nt) {
        const int row = wn * 64 + nt * 16 + col;
        bf[nt] = *reinterpret_cast<const bf16x8*>(&Bs[row * 64 + ((ks + quad) ^ (col & 7)) * 8]);
      }
#pragma unroll
      for (int mt = 0; mt < MT; ++mt)
#pragma unroll
        for (int nt = 0; nt < 4; ++nt)
          acc[mt][nt] = __builtin_amdgcn_mfma_f32_16x16x32_bf16(af[mt], bf[nt], acc[mt][nt], 0, 0, 0);
    }
  }

#pragma unroll
  for (int mt = 0; mt < MT; ++mt) {
#pragma unroll
    for (int r = 0; r < 4; ++r) {
      const int grow = bm * BM + wm * (BM / 2) + mt * 16 + quad * 4 + r;
#pragma unroll
      for (int nt = 0; nt < 4; ++nt) {
        const int gcol = bn * 128 + wn * 64 + nt * 16 + col;
        const float val = acc[mt][nt][r] + bias[gcol];
        if constexpr (MODE == 0) {
          outb[(size_t)grow * N + gcol] = f2bf(gelu_f(val));
        } else if constexpr (MODE == 1) {
          outf[(size_t)grow * N + gcol] = resid[(size_t)grow * N + gcol] + val;
        } else {
          const int which = gcol >> 10, c = gcol & 1023;
          const int hh = c >> 6, dd = c & 63;
          const int bb = grow >> 11, tt = grow & 2047;
          if (which == 0)
            qo[((bb * H_ + hh) * (size_t)T_ + tt) * HD_ + dd] = f2bf(val * 0.125f);
          else if (which == 1)
            ko[((bb * H_ + hh) * (size_t)T_ + tt) * HD_ + dd] = f2bf(val);
          else
            vto[((bb * H_ + hh) * (size_t)HD_ + dd) * T_ + tt] = f2bf(val);
        }
      }
    }
  }
}

// ---------------- flash attention (causal), bf16 MFMA, no-max online softmax ----------------
// grid: (B*H, T/32), qt reversed; block 128 = 2 waves, each wave owns 16 q rows.
// R6 chunk structure (64-key chunks, single-buffer K/V LDS, 2 barriers/chunk,
// reg-prefetch of next chunk) but with 2-wave barrier groups and 7 blocks/CU.
// Row-sum via ones-MFMA (exp-safe: q pre-scaled 1/8). LDS rows padded to 68.
#define PSTR 68
__global__ __launch_bounds__(128, 3) void attn_kernel(
    const u16* __restrict__ q, const u16* __restrict__ k,
    const u16* __restrict__ vt, u16* __restrict__ y) {
  const int bh  = blockIdx.x;
  const int qt  = (T_ / 32 - 1) - blockIdx.y;   // heavy blocks first
  const int tid = threadIdx.x;
  const int wave = tid >> 6, lane = tid & 63;
  const int col = lane & 15, quad = lane >> 4;
  const int b = bh >> 4, h = bh & 15;
  const int r0w = qt * 32 + wave * 16;   // wave's 16 q rows

  __shared__ __align__(16) u16 Klds[64 * PSTR];     // [key][d]
  __shared__ __align__(16) u16 Vtlds[64 * PSTR];    // [d][key]
  __shared__ __align__(16) u16 Plds[2 * 16 * PSTR]; // per-wave [qrow][key]
  u16* pw = Plds + wave * 16 * PSTR;

  bf16x8 aq[2];
#pragma unroll
  for (int j = 0; j < 2; ++j)
    aq[j] = *reinterpret_cast<const bf16x8*>(
        &q[((size_t)bh * T_ + r0w + col) * HD_ + j * 32 + quad * 8]);

  bf16x8 ones;
#pragma unroll
  for (int jj = 0; jj < 8; ++jj) ones[jj] = (__bf16)1.0f;

  f32x4 o[4] = {};
  f32x4 l_acc = {};

  const int srow = tid >> 3, spart = tid & 7;   // 16 rows x 8 parts; x4 row-groups
  const u16* kbase  = k  + (size_t)bh * T_ * HD_ + (size_t)srow * HD_ + spart * 8;
  const u16* vtbase = vt + (size_t)bh * HD_ * T_ + (size_t)srow * T_ + spart * 8;

  const int kb_last = (qt >> 1) * 64;   // last 64-key chunk this block needs

  // prefetch chunk 0 into regs
  uint4 kv[4], vv[4];
#pragma unroll
  for (int i = 0; i < 4; ++i) {
    kv[i] = *reinterpret_cast<const uint4*>(kbase  + (size_t)(16 * i) * HD_);
    vv[i] = *reinterpret_cast<const uint4*>(vtbase + (size_t)(16 * i) * T_);
  }

  for (int kb = 0; kb <= kb_last; kb += 64) {
    // stage current chunk to LDS
#pragma unroll
    for (int i = 0; i < 4; ++i) {
      *reinterpret_cast<uint4*>(&Klds[(srow + 16 * i) * PSTR + spart * 8])  = kv[i];
      *reinterpret_cast<uint4*>(&Vtlds[(srow + 16 * i) * PSTR + spart * 8]) = vv[i];
    }
    __syncthreads();

    // issue next chunk's global loads (latency hidden behind compute below)
    if (kb < kb_last) {
      const int nk = kb + 64;
#pragma unroll
      for (int i = 0; i < 4; ++i) {
        kv[i] = *reinterpret_cast<const uint4*>(kbase  + (size_t)(nk + 16 * i) * HD_);
        vv[i] = *reinterpret_cast<const uint4*>(vtbase + (size_t)(16 * i) * T_ + nk);
      }
    }

    // QK^T: 16 rows x 64 keys
    f32x4 s[4];
#pragma unroll
    for (int n = 0; n < 4; ++n) {
      const bf16x8 bk0 = *reinterpret_cast<const bf16x8*>(&Klds[(n * 16 + col) * PSTR + quad * 8]);
      const bf16x8 bk1 = *reinterpret_cast<const bf16x8*>(&Klds[(n * 16 + col) * PSTR + 32 + quad * 8]);
      f32x4 z = {};
      z = __builtin_amdgcn_mfma_f32_16x16x32_bf16(aq[0], bk0, z, 0, 0, 0);
      s[n] = __builtin_amdgcn_mfma_f32_16x16x32_bf16(aq[1], bk1, z, 0, 0, 0);
    }

    // exp + causal mask (diagonal chunk only); write P
    const bool domask = (kb + 63 > r0w);
#pragma unroll
    for (int n = 0; n < 4; ++n) {
#pragma unroll
      for (int r = 0; r < 4; ++r) {
        float sv = s[n][r];
        if (domask) {
          const int key = kb + n * 16 + col;
          const int row = r0w + quad * 4 + r;
          sv = (key <= row) ? sv : -1e30f;
        }
        pw[(quad * 4 + r) * PSTR + n * 16 + col] = f2bf(__expf(sv));
      }
    }
    __builtin_amdgcn_s_waitcnt(0xC07F);  // lgkmcnt(0): own-wave P writes visible

    const bf16x8 ap0 = *reinterpret_cast<const bf16x8*>(&pw[col * PSTR + quad * 8]);
    const bf16x8 ap1 = *reinterpret_cast<const bf16x8*>(&pw[col * PSTR + 32 + quad * 8]);
    l_acc = __builtin_amdgcn_mfma_f32_16x16x32_bf16(ap0, ones, l_acc, 0, 0, 0);
    l_acc = __builtin_amdgcn_mfma_f32_16x16x32_bf16(ap1, ones, l_acc, 0, 0, 0);
#pragma unroll
    for (int n = 0; n < 4; ++n) {
      const bf16x8 bv0 = *reinterpret_cast<const bf16x8*>(&Vtlds[(n * 16 + col) * PSTR + quad * 8]);
      const bf16x8 bv1 = *reinterpret_cast<const bf16x8*>(&Vtlds[(n * 16 + col) * PSTR + 32 + quad * 8]);
      o[n] = __builtin_amdgcn_mfma_f32_16x16x32_bf16(ap0, bv0, o[n], 0, 0, 0);
      o[n] = __builtin_amdgcn_mfma_f32_16x16x32_bf16(ap1, bv1, o[n], 0, 0, 0);
    }
    __syncthreads();  // both waves done reading K/V before next chunk's ds_write
  }

#pragma unroll
  for (int r = 0; r < 4; ++r) {
    const int qrow = r0w + quad * 4 + r;
    const float inv = 1.0f / l_acc[r];
#pragma unroll
    for (int n = 0; n < 4; ++n)
      y[((size_t)b * T_ + qrow) * C_ + h * HD_ + n * 16 + col] = f2bf(o[n][r] * inv);
  }
}

extern "C" void kernel_launch(void* const* d_in, const int* in_sizes, int n_in,
                              void* d_out, int out_size, void* d_ws, size_t ws_size,
                              hipStream_t stream) {
  const float* x      = (const float*)d_in[0];
  const float* ln1_g  = (const float*)d_in[1];
  const float* ln1_b  = (const float*)d_in[2];
  const float* W_attn = (const float*)d_in[3];
  const float* b_attn = (const float*)d_in[4];
  const float* W_proj = (const float*)d_in[5];
  const float* b_proj = (const float*)d_in[6];
  const float* ln2_g  = (const float*)d_in[7];
  const float* ln2_b  = (const float*)d_in[8];
  const float* W_fc   = (const float*)d_in[9];
  const float* b_fc   = (const float*)d_in[10];
  const float* W_fc2  = (const float*)d_in[11];
  const float* b_fc2  = (const float*)d_in[12];
  float* out = (float*)d_out;

  char* p = (char*)d_ws;
  auto alloc = [&](size_t bytes) {
    char* r = p;
    p += (bytes + 255) & ~(size_t)255;
    return r;
  };
  u16*   h1      = (u16*)alloc((size_t)M_TOT * C_ * 2);
  u16*   wt_attn = (u16*)alloc((size_t)3 * C_ * C_ * 2);
  u16*   wt_proj = (u16*)alloc((size_t)C_ * C_ * 2);
  u16*   wt_fc   = (u16*)alloc((size_t)4 * C_ * C_ * 2);
  u16*   wt_fc2  = (u16*)alloc((size_t)C_ * 4 * C_ * 2);
  u16*   qbuf    = (u16*)alloc((size_t)M_TOT * C_ * 2);
  u16*   kbuf    = (u16*)alloc((size_t)M_TOT * C_ * 2);
  u16*   vtbuf   = (u16*)alloc((size_t)M_TOT * C_ * 2);
  u16*   ybuf    = (u16*)alloc((size_t)M_TOT * C_ * 2);
  float* x2      = (float*)alloc((size_t)M_TOT * C_ * 4);
  u16*   h2      = (u16*)alloc((size_t)M_TOT * C_ * 2);
  u16*   act     = (u16*)alloc((size_t)M_TOT * 4 * C_ * 2);

  // weights: fp32 [K][N] -> bf16 [N][K]
  transpose_bf16_kernel<<<dim3(96, 32),  256, 0, stream>>>(W_attn, wt_attn, 1024, 3072);
  transpose_bf16_kernel<<<dim3(32, 32),  256, 0, stream>>>(W_proj, wt_proj, 1024, 1024);
  transpose_bf16_kernel<<<dim3(128, 32), 256, 0, stream>>>(W_fc,   wt_fc,   1024, 4096);
  transpose_bf16_kernel<<<dim3(32, 128), 256, 0, stream>>>(W_fc2,  wt_fc2,  4096, 1024);

  // ln1
  ln_bf16_kernel<<<M_TOT, 256, 0, stream>>>(x, ln1_g, ln1_b, h1);

  // qkv = h1 @ W_attn + b_attn -> q(scaled)/k/vt   (768 blocks; 32 bm rows -> logPer=2)
  gemm_kernel<3, 128><<<dim3(24, 32), 256, 0, stream>>>(h1, wt_attn, b_attn, nullptr,
                                                        nullptr, nullptr, qbuf, kbuf, vtbuf,
                                                        4096, 3072, 1024, 2);
  // causal flash attention -> y [B,T,C]  (2048 blocks of 2 waves, 32-row q-tiles)
  attn_kernel<<<dim3(32, 64), 128, 0, stream>>>(qbuf, kbuf, vtbuf, ybuf);

  // x2 = x + y @ W_proj + b_proj    (64x128 tile, 512 blocks; 64 bm rows -> logPer=3)
  gemm_kernel<1, 64><<<dim3(8, 64), 256, 0, stream>>>(ybuf, wt_proj, b_proj, x,
                                                      x2, nullptr, nullptr, nullptr, nullptr,
                                                      4096, 1024, 1024, 3);
  // ln2
  ln_bf16_kernel<<<M_TOT, 256, 0, stream>>>(x2, ln2_g, ln2_b, h2);

  // act = gelu(h2 @ W_fc + b_fc)    (1024 blocks; 32 bm rows -> logPer=2)
  gemm_kernel<0, 128><<<dim3(32, 32), 256, 0, stream>>>(h2, wt_fc, b_fc, nullptr,
                                                        nullptr, act, nullptr, nullptr, nullptr,
                                                        4096, 4096, 1024, 2);
  // out = x2 + act @ W_fc2 + b_fc2  (64x128 tile, 512 blocks; 64 bm rows -> logPer=3)
  gemm_kernel<1, 64><<<dim3(8, 64), 256, 0, stream>>>(act, wt_fc2, b_fc2, x2,
                                                      out, nullptr, nullptr, nullptr, nullptr,
                                                      4096, 1024, 4096, 3);
}

// Round 11
// 327.189 us; speedup vs baseline: 1.4273x; 1.4273x over previous
//
#include <hip/hip_runtime.h>
#include <hip/hip_bf16.h>
#include <cstdint>
#include <cstddef>

// Transformer block: B=2, T=2048, C=1024, H=16, HD=64.
// bf16 MFMA for all GEMM-shaped compute; fp32 for LN stats / softmax sums / residuals.
// R11: revert to R6 base (best: 338 us). Changes:
//  (a) attn S^T-swap: compute S^T = K*Q^T (operand swap, identical fragment reads);
//      C-layout then gives 4 consecutive keys/lane -> P written as 4 packed
//      ds_write_b64 instead of 16 scalar ds_write_u16 (shorter lgkm chain).
//  (b) prep fusion: 4 weight transposes + ln1 in ONE kernel (11 -> 7 dispatches).
//  NOTE: prefetch regs must stay SCALARS (R10's arrays spilled to scratch: 420MB writes).
#define B_  2
#define T_  2048
#define C_  1024
#define H_  16
#define HD_ 64
#define M_TOT 4096   // B*T

typedef __bf16 bf16x8 __attribute__((ext_vector_type(8)));
typedef float  f32x4  __attribute__((ext_vector_type(4)));
typedef unsigned short u16;

__device__ __forceinline__ u16 f2bf(float f) {
  __hip_bfloat16 h = __float2bfloat16(f);
  return __builtin_bit_cast(u16, h);
}

// async global->LDS, 16B per lane; LDS dest is wave-uniform base + lane*16.
__device__ __forceinline__ void async_cp16(const u16* g, u16* l) {
  __builtin_amdgcn_global_load_lds(
      (const __attribute__((address_space(1))) void*)g,
      (__attribute__((address_space(3))) void*)l, 16, 0, 0);
}

// gelu_tanh: 0.5*x*(1+tanh z) == x * sigmoid(2z); overflow-safe via negative exp.
__device__ __forceinline__ float gelu_f(float x) {
  const float z = 0.7978845608028654f * (x + 0.044715f * x * x * x);
  return x / (1.0f + __expf(-2.0f * z));
}

// ---------------- LayerNorm (fp32 in -> bf16 out), one block per row ----------------
__device__ __forceinline__ void ln_row(
    const float* __restrict__ x, const float* __restrict__ g,
    const float* __restrict__ b, u16* __restrict__ out, int row, int tid) {
  const float4 v = reinterpret_cast<const float4*>(x)[row * 256 + tid];
  float s  = v.x + v.y + v.z + v.w;
  float sq = v.x * v.x + v.y * v.y + v.z * v.z + v.w * v.w;
#pragma unroll
  for (int off = 32; off > 0; off >>= 1) {
    s  += __shfl_xor(s, off);
    sq += __shfl_xor(sq, off);
  }
  __shared__ float red[8];
  const int wave = tid >> 6;
  if ((tid & 63) == 0) { red[wave] = s; red[4 + wave] = sq; }
  __syncthreads();
  s  = red[0] + red[1] + red[2] + red[3];
  sq = red[4] + red[5] + red[6] + red[7];
  const float mu   = s * (1.0f / 1024.0f);
  const float rstd = rsqrtf(sq * (1.0f / 1024.0f) - mu * mu + 1e-5f);
  const float4 gv = reinterpret_cast<const float4*>(g)[tid];
  const float4 bv = reinterpret_cast<const float4*>(b)[tid];
  ushort4 o;
  o.x = f2bf((v.x - mu) * rstd * gv.x + bv.x);
  o.y = f2bf((v.y - mu) * rstd * gv.y + bv.y);
  o.z = f2bf((v.z - mu) * rstd * gv.z + bv.z);
  o.w = f2bf((v.w - mu) * rstd * gv.w + bv.w);
  reinterpret_cast<ushort4*>(out)[row * 256 + tid] = o;
}

__global__ __launch_bounds__(256) void ln_bf16_kernel(
    const float* __restrict__ x, const float* __restrict__ g,
    const float* __restrict__ b, u16* __restrict__ out) {
  ln_row(x, g, b, out, blockIdx.x, threadIdx.x);
}

// ---------------- prep: ln1 + all 4 weight transposes (fp32 [K][N] -> bf16 [N][K]) --------
// blocks [0,4096): ln1 rows; [4096,16384): 32x32 transpose tiles of the 4 weights.
__global__ __launch_bounds__(256) void prep_kernel(
    const float* __restrict__ x, const float* __restrict__ ln1_g,
    const float* __restrict__ ln1_b, u16* __restrict__ h1,
    const float* __restrict__ W_attn, u16* __restrict__ wt_attn,
    const float* __restrict__ W_proj, u16* __restrict__ wt_proj,
    const float* __restrict__ W_fc,   u16* __restrict__ wt_fc,
    const float* __restrict__ W_fc2,  u16* __restrict__ wt_fc2) {
  int bid = blockIdx.x;
  if (bid < 4096) { ln_row(x, ln1_g, ln1_b, h1, bid, threadIdx.x); return; }
  bid -= 4096;
  const float* W; u16* Wt; int K, N, nx;
  if (bid < 3072)      {              W = W_attn; Wt = wt_attn; K = 1024; N = 3072; nx = 96; }
  else if (bid < 4096) { bid -= 3072; W = W_proj; Wt = wt_proj; K = 1024; N = 1024; nx = 32; }
  else if (bid < 8192) { bid -= 4096; W = W_fc;   Wt = wt_fc;   K = 1024; N = 4096; nx = 128; }
  else                 { bid -= 8192; W = W_fc2;  Wt = wt_fc2;  K = 4096; N = 1024; nx = 32; }
  const int n0 = (bid % nx) * 32, k0 = (bid / nx) * 32;
  __shared__ float tile[32][33];
  const int tx = threadIdx.x & 31;
  const int ty = threadIdx.x >> 5;  // 0..7
#pragma unroll
  for (int i = 0; i < 4; ++i)
    tile[ty + 8 * i][tx] = W[(k0 + ty + 8 * i) * (size_t)N + n0 + tx];
  __syncthreads();
#pragma unroll
  for (int i = 0; i < 4; ++i)
    Wt[(n0 + ty + 8 * i) * (size_t)K + k0 + tx] = f2bf(tile[tx][ty + 8 * i]);
}

// ---------------- bf16 MFMA GEMM: C[M,N] = A[M,K] @ Bt[N,K]^T, fused epilogues -------------
// Tile: BM x 128, BK=64. XOR-swizzled LDS (conflict-free), XCD-aware block swizzle.
// MODE 0: +bias, gelu -> bf16 out                      (fc)
// MODE 1: +bias, +resid(fp32) -> fp32                  (proj, fc2)
// MODE 3: +bias, scatter q(scaled)/k [B,H,T,HD], v transposed [B,H,HD,T]  (qkv)
template <int MODE, int BM>
__global__ __launch_bounds__(256, 2) void gemm_kernel(
    const u16* __restrict__ A, const u16* __restrict__ Bt,
    const float* __restrict__ bias, const float* __restrict__ resid,
    float* __restrict__ outf, u16* __restrict__ outb,
    u16* __restrict__ qo, u16* __restrict__ ko, u16* __restrict__ vto,
    int M, int N, int K, int logPer) {
  constexpr int MT = BM / 32;            // m-tiles of 16 per wave
  constexpr int AI = BM / 32;            // A staging instrs per wave (8 rows each)
  __shared__ __align__(16) u16 As[BM * 64];
  __shared__ __align__(16) u16 Bs[128 * 64];
  const int tid  = threadIdx.x;
  const int wave = tid >> 6, lane = tid & 63;
  const int col  = lane & 15, quad = lane >> 4;
  const int wm   = wave >> 1, wn = wave & 1;

  const int flat = blockIdx.y * gridDim.x + blockIdx.x;
  const int xcd = flat & 7, sl = flat >> 3;
  const int per = 1 << logPer;
  const int bm = (xcd << logPer) + (sl & (per - 1));
  const int bn = sl >> logPer;

  const int srow = lane >> 3, sc8 = lane & 7;
  const int kcs = (sc8 ^ srow) * 8;                  // XOR-swizzled global k offset
  const u16* ap = A  + (size_t)(bm * BM + wave * (BM / 4) + srow) * K + kcs;
  const u16* bp = Bt + (size_t)(bn * 128 + wave * 32 + srow) * K + kcs;
  u16* as_dst = As + wave * (BM / 4) * 64;
  u16* bs_dst = Bs + wave * 2048;

  f32x4 acc[MT][4] = {};

  for (int k0 = 0; k0 < K; k0 += 64) {
    __syncthreads();
#pragma unroll
    for (int i = 0; i < AI; ++i)
      async_cp16(ap + k0 + i * 8 * (size_t)K, as_dst + i * 512);
#pragma unroll
    for (int i = 0; i < 4; ++i)
      async_cp16(bp + k0 + i * 8 * (size_t)K, bs_dst + i * 512);
    __syncthreads();
#pragma unroll
    for (int kh = 0; kh < 2; ++kh) {
      const int ks = kh * 4;
      bf16x8 af[MT], bf[4];
#pragma unroll
      for (int mt = 0; mt < MT; ++mt) {
        const int row = wm * (BM / 2) + mt * 16 + col;
        af[mt] = *reinterpret_cast<const bf16x8*>(&As[row * 64 + ((ks + quad) ^ (col & 7)) * 8]);
      }
#pragma unroll
      for (int nt = 0; nt < 4; ++nt) {
        const int row = wn * 64 + nt * 16 + col;
        bf[nt] = *reinterpret_cast<const bf16x8*>(&Bs[row * 64 + ((ks + quad) ^ (col & 7)) * 8]);
      }
#pragma unroll
      for (int mt = 0; mt < MT; ++mt)
#pragma unroll
        for (int nt = 0; nt < 4; ++nt)
          acc[mt][nt] = __builtin_amdgcn_mfma_f32_16x16x32_bf16(af[mt], bf[nt], acc[mt][nt], 0, 0, 0);
    }
  }

#pragma unroll
  for (int mt = 0; mt < MT; ++mt) {
#pragma unroll
    for (int r = 0; r < 4; ++r) {
      const int grow = bm * BM + wm * (BM / 2) + mt * 16 + quad * 4 + r;
#pragma unroll
      for (int nt = 0; nt < 4; ++nt) {
        const int gcol = bn * 128 + wn * 64 + nt * 16 + col;
        const float val = acc[mt][nt][r] + bias[gcol];
        if constexpr (MODE == 0) {
          outb[(size_t)grow * N + gcol] = f2bf(gelu_f(val));
        } else if constexpr (MODE == 1) {
          outf[(size_t)grow * N + gcol] = resid[(size_t)grow * N + gcol] + val;
        } else {
          const int which = gcol >> 10, c = gcol & 1023;
          const int hh = c >> 6, dd = c & 63;
          const int bb = grow >> 11, tt = grow & 2047;
          if (which == 0)
            qo[((bb * H_ + hh) * (size_t)T_ + tt) * HD_ + dd] = f2bf(val * 0.125f);
          else if (which == 1)
            ko[((bb * H_ + hh) * (size_t)T_ + tt) * HD_ + dd] = f2bf(val);
          else
            vto[((bb * H_ + hh) * (size_t)HD_ + dd) * T_ + tt] = f2bf(val);
        }
      }
    }
  }
}

// ---------------- flash attention (causal), bf16 MFMA, no-max online softmax ----------------
// grid: (B*H, T/64), qt reversed; block 256 = 4 waves, each wave owns 16 q rows.
// R6 chunk structure (64-key chunks, single-buffer K/V LDS, 2 barriers/chunk,
// SCALAR reg-prefetch). S^T-swap: S^T = K*Q^T via operand swap (identical frag
// reads); P stored as 4 packed ds_write_b64 (4 consecutive keys/lane) instead of
// 16 scalar writes. Row-sum via ones-MFMA (exp-safe: q pre-scaled 1/8).
#define PSTR 68
__global__ __launch_bounds__(256, 4) void attn_kernel(
    const u16* __restrict__ q, const u16* __restrict__ k,
    const u16* __restrict__ vt, u16* __restrict__ y) {
  const int bh  = blockIdx.x;
  const int qt  = (T_ / 64 - 1) - blockIdx.y;   // heavy blocks first
  const int tid = threadIdx.x;
  const int wave = tid >> 6, lane = tid & 63;
  const int col = lane & 15, quad = lane >> 4;
  const int b = bh >> 4, h = bh & 15;
  const int r0w = qt * 64 + wave * 16;   // wave's 16 q rows

  __shared__ __align__(16) u16 Klds[64 * PSTR];     // [key][d]
  __shared__ __align__(16) u16 Vtlds[64 * PSTR];    // [d][key]
  __shared__ __align__(16) u16 Plds[4 * 16 * PSTR]; // per-wave [qrow][key]
  u16* pw = Plds + wave * 16 * PSTR;

  bf16x8 aq0 = *reinterpret_cast<const bf16x8*>(
      &q[((size_t)bh * T_ + r0w + col) * HD_ + quad * 8]);
  bf16x8 aq1 = *reinterpret_cast<const bf16x8*>(
      &q[((size_t)bh * T_ + r0w + col) * HD_ + 32 + quad * 8]);

  bf16x8 ones;
#pragma unroll
  for (int jj = 0; jj < 8; ++jj) ones[jj] = (__bf16)1.0f;

  f32x4 o[4] = {};
  f32x4 l_acc = {};

  const int srow = tid >> 3, spart = tid & 7;   // 32 rows x 8 parts
  const u16* kbase  = k  + (size_t)bh * T_ * HD_ + (size_t)srow * HD_ + spart * 8;
  const u16* vtbase = vt + (size_t)bh * HD_ * T_ + (size_t)srow * T_ + spart * 8;

  const int kb_last = qt * 64;

  // prefetch chunk 0 into SCALAR regs (arrays spill to scratch — R10 lesson)
  uint4 kv0 = *reinterpret_cast<const uint4*>(kbase);
  uint4 kv1 = *reinterpret_cast<const uint4*>(kbase + 32 * HD_);
  uint4 kv2 = *reinterpret_cast<const uint4*>(vtbase);
  uint4 kv3 = *reinterpret_cast<const uint4*>(vtbase + 32 * T_);

  for (int kb = 0; kb <= kb_last; kb += 64) {
    // stage current chunk to LDS
    *reinterpret_cast<uint4*>(&Klds[srow * PSTR + spart * 8])         = kv0;
    *reinterpret_cast<uint4*>(&Klds[(srow + 32) * PSTR + spart * 8])  = kv1;
    *reinterpret_cast<uint4*>(&Vtlds[srow * PSTR + spart * 8])        = kv2;
    *reinterpret_cast<uint4*>(&Vtlds[(srow + 32) * PSTR + spart * 8]) = kv3;
    __syncthreads();

    // issue next chunk's global loads (latency hidden behind compute below)
    if (kb < kb_last) {
      const int nk = kb + 64;
      kv0 = *reinterpret_cast<const uint4*>(kbase + (size_t)nk * HD_);
      kv1 = *reinterpret_cast<const uint4*>(kbase + (size_t)nk * HD_ + 32 * HD_);
      kv2 = *reinterpret_cast<const uint4*>(vtbase + nk);
      kv3 = *reinterpret_cast<const uint4*>(vtbase + 32 * T_ + nk);
    }

    // S^T = K * Q^T : 64 keys x 16 q. A-frag = K rows, B-frag = Q rows (swap).
    // C layout: key-row = n*16 + quad*4 + r, q-col = col.
    f32x4 st[4];
#pragma unroll
    for (int n = 0; n < 4; ++n) {
      const bf16x8 ak0 = *reinterpret_cast<const bf16x8*>(&Klds[(n * 16 + col) * PSTR + quad * 8]);
      const bf16x8 ak1 = *reinterpret_cast<const bf16x8*>(&Klds[(n * 16 + col) * PSTR + 32 + quad * 8]);
      f32x4 z = {};
      z = __builtin_amdgcn_mfma_f32_16x16x32_bf16(ak0, aq0, z, 0, 0, 0);
      st[n] = __builtin_amdgcn_mfma_f32_16x16x32_bf16(ak1, aq1, z, 0, 0, 0);
    }

    // exp + causal mask; pack 4 consecutive keys -> one b64 write into P[q][key]
    const bool domask = (kb + 63 > r0w);
#pragma unroll
    for (int n = 0; n < 4; ++n) {
      ushort4 pk;
#pragma unroll
      for (int r = 0; r < 4; ++r) {
        float sv = st[n][r];
        if (domask) {
          const int key = kb + n * 16 + quad * 4 + r;
          const int row = r0w + col;
          sv = (key <= row) ? sv : -1e30f;
        }
        reinterpret_cast<u16*>(&pk)[r] = f2bf(__expf(sv));
      }
      *reinterpret_cast<ushort4*>(&pw[col * PSTR + n * 16 + quad * 4]) = pk;
    }
    __builtin_amdgcn_s_waitcnt(0xC07F);  // lgkmcnt(0): own-wave P writes visible

    const bf16x8 ap0 = *reinterpret_cast<const bf16x8*>(&pw[col * PSTR + quad * 8]);
    const bf16x8 ap1 = *reinterpret_cast<const bf16x8*>(&pw[col * PSTR + 32 + quad * 8]);
    l_acc = __builtin_amdgcn_mfma_f32_16x16x32_bf16(ap0, ones, l_acc, 0, 0, 0);
    l_acc = __builtin_amdgcn_mfma_f32_16x16x32_bf16(ap1, ones, l_acc, 0, 0, 0);
#pragma unroll
    for (int n = 0; n < 4; ++n) {
      const bf16x8 bv0 = *reinterpret_cast<const bf16x8*>(&Vtlds[(n * 16 + col) * PSTR + quad * 8]);
      const bf16x8 bv1 = *reinterpret_cast<const bf16x8*>(&Vtlds[(n * 16 + col) * PSTR + 32 + quad * 8]);
      o[n] = __builtin_amdgcn_mfma_f32_16x16x32_bf16(ap0, bv0, o[n], 0, 0, 0);
      o[n] = __builtin_amdgcn_mfma_f32_16x16x32_bf16(ap1, bv1, o[n], 0, 0, 0);
    }
    __syncthreads();  // all waves done reading K/V before next chunk's ds_write
  }

#pragma unroll
  for (int r = 0; r < 4; ++r) {
    const int qrow = r0w + quad * 4 + r;
    const float inv = 1.0f / l_acc[r];
#pragma unroll
    for (int n = 0; n < 4; ++n)
      y[((size_t)b * T_ + qrow) * C_ + h * HD_ + n * 16 + col] = f2bf(o[n][r] * inv);
  }
}

extern "C" void kernel_launch(void* const* d_in, const int* in_sizes, int n_in,
                              void* d_out, int out_size, void* d_ws, size_t ws_size,
                              hipStream_t stream) {
  const float* x      = (const float*)d_in[0];
  const float* ln1_g  = (const float*)d_in[1];
  const float* ln1_b  = (const float*)d_in[2];
  const float* W_attn = (const float*)d_in[3];
  const float* b_attn = (const float*)d_in[4];
  const float* W_proj = (const float*)d_in[5];
  const float* b_proj = (const float*)d_in[6];
  const float* ln2_g  = (const float*)d_in[7];
  const float* ln2_b  = (const float*)d_in[8];
  const float* W_fc   = (const float*)d_in[9];
  const float* b_fc   = (const float*)d_in[10];
  const float* W_fc2  = (const float*)d_in[11];
  const float* b_fc2  = (const float*)d_in[12];
  float* out = (float*)d_out;

  char* p = (char*)d_ws;
  auto alloc = [&](size_t bytes) {
    char* r = p;
    p += (bytes + 255) & ~(size_t)255;
    return r;
  };
  u16*   h1      = (u16*)alloc((size_t)M_TOT * C_ * 2);
  u16*   wt_attn = (u16*)alloc((size_t)3 * C_ * C_ * 2);
  u16*   wt_proj = (u16*)alloc((size_t)C_ * C_ * 2);
  u16*   wt_fc   = (u16*)alloc((size_t)4 * C_ * C_ * 2);
  u16*   wt_fc2  = (u16*)alloc((size_t)C_ * 4 * C_ * 2);
  u16*   qbuf    = (u16*)alloc((size_t)M_TOT * C_ * 2);
  u16*   kbuf    = (u16*)alloc((size_t)M_TOT * C_ * 2);
  u16*   vtbuf   = (u16*)alloc((size_t)M_TOT * C_ * 2);
  u16*   ybuf    = (u16*)alloc((size_t)M_TOT * C_ * 2);
  float* x2      = (float*)alloc((size_t)M_TOT * C_ * 4);
  u16*   h2      = (u16*)alloc((size_t)M_TOT * C_ * 2);
  u16*   act     = (u16*)alloc((size_t)M_TOT * 4 * C_ * 2);

  // prep: ln1 + all 4 weight transposes in one launch
  prep_kernel<<<16384, 256, 0, stream>>>(x, ln1_g, ln1_b, h1,
                                         W_attn, wt_attn, W_proj, wt_proj,
                                         W_fc, wt_fc, W_fc2, wt_fc2);

  // qkv = h1 @ W_attn + b_attn -> q(scaled)/k/vt   (768 blocks; 32 bm rows -> logPer=2)
  gemm_kernel<3, 128><<<dim3(24, 32), 256, 0, stream>>>(h1, wt_attn, b_attn, nullptr,
                                                        nullptr, nullptr, qbuf, kbuf, vtbuf,
                                                        4096, 3072, 1024, 2);
  // causal flash attention -> y [B,T,C]   (1024 blocks, 64-row q-tiles)
  attn_kernel<<<dim3(32, 32), 256, 0, stream>>>(qbuf, kbuf, vtbuf, ybuf);

  // x2 = x + y @ W_proj + b_proj    (64x128 tile, 512 blocks; 64 bm rows -> logPer=3)
  gemm_kernel<1, 64><<<dim3(8, 64), 256, 0, stream>>>(ybuf, wt_proj, b_proj, x,
                                                      x2, nullptr, nullptr, nullptr, nullptr,
                                                      4096, 1024, 1024, 3);
  // ln2
  ln_bf16_kernel<<<M_TOT, 256, 0, stream>>>(x2, ln2_g, ln2_b, h2);

  // act = gelu(h2 @ W_fc + b_fc)    (1024 blocks; 32 bm rows -> logPer=2)
  gemm_kernel<0, 128><<<dim3(32, 32), 256, 0, stream>>>(h2, wt_fc, b_fc, nullptr,
                                                        nullptr, act, nullptr, nullptr, nullptr,
                                                        4096, 4096, 1024, 2);
  // out = x2 + act @ W_fc2 + b_fc2  (64x128 tile, 512 blocks; 64 bm rows -> logPer=3)
  gemm_kernel<1, 64><<<dim3(8, 64), 256, 0, stream>>>(act, wt_fc2, b_fc2, x2,
                                                      out, nullptr, nullptr, nullptr, nullptr,
                                                      4096, 1024, 4096, 3);
}